// Round 2
// baseline (13317.311 us; speedup 1.0000x reference)
//
#include <hip/hip_runtime.h>
#include <cstdio>

typedef __attribute__((ext_vector_type(8))) short short8_t;
typedef __attribute__((ext_vector_type(8))) unsigned short ushort8_t;
typedef __attribute__((ext_vector_type(4))) unsigned short us4;
typedef __attribute__((ext_vector_type(4))) float f32x4;

__device__ __forceinline__ unsigned short f2bf(float f) {
  unsigned u = __float_as_uint(f);
  u = u + 0x7FFFu + ((u >> 16) & 1u);
  return (unsigned short)(u >> 16);
}
__device__ __forceinline__ float bf2f(unsigned short h) {
  return __uint_as_float((unsigned)h << 16);
}
__device__ __forceinline__ float lrelu(float x) { return x > 0.f ? x : 0.2f * x; }

// ---------------- conversion / transpose ----------------

// float -> bf16, float4 granularity; zero-fills [ns4, nd4) (row padding)
__global__ void k_f32_to_bf16(const float* __restrict__ src, unsigned short* __restrict__ dst,
                              size_t ns4, size_t nd4) {
  size_t i = (size_t)blockIdx.x * blockDim.x + threadIdx.x;
  if (i >= nd4) return;
  float4 v = make_float4(0.f, 0.f, 0.f, 0.f);
  if (i < ns4) v = ((const float4*)src)[i];
  us4 u = {f2bf(v.x), f2bf(v.y), f2bf(v.z), f2bf(v.w)};
  ((us4*)dst)[i] = u;
}

// W[256][256] f32 -> Wt[256][256] bf16 transposed (Wt[n][k] = W[k][n])
__global__ void k_transpose_w(const float* __restrict__ W, unsigned short* __restrict__ Wt) {
  int k = blockIdx.x, n = threadIdx.x;
  Wt[n * 256 + k] = f2bf(W[k * 256 + n]);
}

// ---------------- fused GEMM (+bias+lrelu+skip+LN) ------------------------------------
// C[M,256] = LN(lrelu(A@W + b) [+ skip]); A bf16 [Mpad,256], Bt = W^T bf16.
// block = 256 thr (4 waves); tile 64x256; wave w holds 16 COMPLETE rows -> LN in epilogue.
template <int HAS_SKIP>
__global__ __launch_bounds__(256) void k_gemm_ln(const unsigned short* A,
                                                 const unsigned short* __restrict__ Bt,
                                                 const float* __restrict__ bias,
                                                 const float* __restrict__ gamma,
                                                 const float* __restrict__ beta,
                                                 const unsigned short* skip,
                                                 unsigned short* outb, int rows) {
  __shared__ unsigned short As[64][40];  // +8 pad, rows 80B (16B-aligned)
  __shared__ unsigned short Bs[256][40];
  int tid = threadIdx.x;
  int wave = tid >> 6, lane = tid & 63;
  int quad = lane >> 4, l16 = lane & 15;
  size_t row0 = (size_t)blockIdx.x * 64;

  f32x4 acc[16];
#pragma unroll
  for (int i = 0; i < 16; i++) acc[i] = (f32x4){0.f, 0.f, 0.f, 0.f};

  int ar = tid >> 2, ac = (tid & 3) * 8;
  for (int k0 = 0; k0 < 256; k0 += 32) {
    *(ushort8_t*)&As[ar][ac] = *(const ushort8_t*)&A[(row0 + ar) * 256 + k0 + ac];
    const unsigned short* bp = &Bt[(size_t)tid * 256 + k0];
    *(ushort8_t*)&Bs[tid][0] = *(const ushort8_t*)&bp[0];
    *(ushort8_t*)&Bs[tid][8] = *(const ushort8_t*)&bp[8];
    *(ushort8_t*)&Bs[tid][16] = *(const ushort8_t*)&bp[16];
    *(ushort8_t*)&Bs[tid][24] = *(const ushort8_t*)&bp[24];
    __syncthreads();
    short8_t afrag = *(const short8_t*)&As[wave * 16 + l16][quad * 8];
#pragma unroll
    for (int nt = 0; nt < 16; nt++) {
      short8_t bfrag = *(const short8_t*)&Bs[nt * 16 + l16][quad * 8];
      acc[nt] = __builtin_amdgcn_mfma_f32_16x16x32_bf16(afrag, bfrag, acc[nt], 0, 0, 0);
    }
    __syncthreads();
  }

  // epilogue: bias + lrelu (+skip) then LN over each complete row
  size_t rbase = row0 + wave * 16 + quad * 4;  // + r
#pragma unroll
  for (int nt = 0; nt < 16; nt++) {
    int col = nt * 16 + l16;
    float bv = bias[col];
#pragma unroll
    for (int r = 0; r < 4; r++) {
      float x = lrelu(acc[nt][r] + bv);
      if (HAS_SKIP) {
        if (rbase + r < (size_t)rows) x += bf2f(skip[(rbase + r) * 256 + col]);
      }
      acc[nt][r] = x;
    }
  }
  float s[4] = {0, 0, 0, 0}, q[4] = {0, 0, 0, 0};
#pragma unroll
  for (int nt = 0; nt < 16; nt++)
#pragma unroll
    for (int r = 0; r < 4; r++) {
      float x = acc[nt][r];
      s[r] += x;
      q[r] += x * x;
    }
#pragma unroll
  for (int o = 1; o < 16; o <<= 1)
#pragma unroll
    for (int r = 0; r < 4; r++) {
      s[r] += __shfl_xor(s[r], o);
      q[r] += __shfl_xor(q[r], o);
    }
  float mr[4], rs[4];
#pragma unroll
  for (int r = 0; r < 4; r++) {
    float m = s[r] * (1.f / 256.f);
    float v = q[r] * (1.f / 256.f) - m * m;
    mr[r] = m;
    rs[r] = rsqrtf(v + 1e-5f);
  }
#pragma unroll
  for (int nt = 0; nt < 16; nt++) {
    int col = nt * 16 + l16;
    float g = gamma[col], bb = beta[col];
#pragma unroll
    for (int r = 0; r < 4; r++) {
      if (rbase + r < (size_t)rows) {
        float y = (acc[nt][r] - mr[r]) * rs[r] * g + bb;
        outb[(rbase + r) * 256 + col] = f2bf(y);
      }
    }
  }
}

// ---------------- fused GEMM for HGNN: XW (bf16, IN-PLACE over A) + s1 = XW@a1 ----------
__global__ __launch_bounds__(256) void k_gemm_xw(unsigned short* A,
                                                 const unsigned short* __restrict__ Bt,
                                                 const float* __restrict__ a1,
                                                 float* __restrict__ s1, int rows) {
  __shared__ unsigned short As[64][40];
  __shared__ unsigned short Bs[256][40];
  int tid = threadIdx.x;
  int wave = tid >> 6, lane = tid & 63;
  int quad = lane >> 4, l16 = lane & 15;
  size_t row0 = (size_t)blockIdx.x * 64;

  f32x4 acc[16];
#pragma unroll
  for (int i = 0; i < 16; i++) acc[i] = (f32x4){0.f, 0.f, 0.f, 0.f};

  int ar = tid >> 2, ac = (tid & 3) * 8;
  for (int k0 = 0; k0 < 256; k0 += 32) {
    *(ushort8_t*)&As[ar][ac] = *(const ushort8_t*)&A[(row0 + ar) * 256 + k0 + ac];
    const unsigned short* bp = &Bt[(size_t)tid * 256 + k0];
    *(ushort8_t*)&Bs[tid][0] = *(const ushort8_t*)&bp[0];
    *(ushort8_t*)&Bs[tid][8] = *(const ushort8_t*)&bp[8];
    *(ushort8_t*)&Bs[tid][16] = *(const ushort8_t*)&bp[16];
    *(ushort8_t*)&Bs[tid][24] = *(const ushort8_t*)&bp[24];
    __syncthreads();
    short8_t afrag = *(const short8_t*)&As[wave * 16 + l16][quad * 8];
#pragma unroll
    for (int nt = 0; nt < 16; nt++) {
      short8_t bfrag = *(const short8_t*)&Bs[nt * 16 + l16][quad * 8];
      acc[nt] = __builtin_amdgcn_mfma_f32_16x16x32_bf16(afrag, bfrag, acc[nt], 0, 0, 0);
    }
    __syncthreads();
  }

  size_t rbase = row0 + wave * 16 + quad * 4;
  float s[4] = {0, 0, 0, 0};
#pragma unroll
  for (int nt = 0; nt < 16; nt++) {
    float av = a1[nt * 16 + l16];
#pragma unroll
    for (int r = 0; r < 4; r++) s[r] += acc[nt][r] * av;
  }
#pragma unroll
  for (int o = 1; o < 16; o <<= 1)
#pragma unroll
    for (int r = 0; r < 4; r++) s[r] += __shfl_xor(s[r], o);
#pragma unroll
  for (int nt = 0; nt < 16; nt++) {
    int col = nt * 16 + l16;
#pragma unroll
    for (int r = 0; r < 4; r++)
      if (rbase + r < (size_t)rows) A[(rbase + r) * 256 + col] = f2bf(acc[nt][r]);
  }
  if (l16 == 0) {
#pragma unroll
    for (int r = 0; r < 4; r++)
      if (rbase + r < (size_t)rows) s1[rbase + r] = s[r];
  }
}

// ---------------- segment ops ----------------

// dst[didx[e]][:] += bf2f(src[sidx[e]][:])   (one wave per incidence)
__global__ __launch_bounds__(256) void k_scatter_bf(const unsigned short* __restrict__ src,
                                                    const int* __restrict__ sidx,
                                                    const int* __restrict__ didx,
                                                    float* __restrict__ dst, int nE) {
  int wave = threadIdx.x >> 6, lane = threadIdx.x & 63;
  size_t e = (size_t)blockIdx.x * 4 + wave;
  if (e >= (size_t)nE) return;
  int si = sidx[e], di = didx[e];
  us4 u = ((const us4*)(src + (size_t)si * 256))[lane];
  float* dp = dst + (size_t)di * 256 + lane * 4;
  atomicAdd(dp + 0, bf2f(u.x));
  atomicAdd(dp + 1, bf2f(u.y));
  atomicAdd(dp + 2, bf2f(u.z));
  atomicAdd(dp + 3, bf2f(u.w));
}

__global__ void k_count(const int* __restrict__ idx, int* __restrict__ cnt, int nE) {
  int e = blockIdx.x * blockDim.x + threadIdx.x;
  if (e < nE) atomicAdd(&cnt[idx[e]], 1);
}

// ef[r] /= max(cnt,1); s2[r] = dot(ef[r], a2)   (one wave per edge)
__global__ __launch_bounds__(256) void k_ef_norm_s2(float* __restrict__ ef,
                                                    const int* __restrict__ cnt,
                                                    const float* __restrict__ a2,
                                                    float* __restrict__ s2, int rows) {
  int wave = threadIdx.x >> 6, lane = threadIdx.x & 63;
  size_t r = (size_t)blockIdx.x * 4 + wave;
  if (r >= (size_t)rows) return;
  int c = cnt[r];
  float inv = 1.f / (float)(c > 1 ? c : 1);
  float4 v = ((float4*)(ef + r * 256))[lane];
  v.x *= inv; v.y *= inv; v.z *= inv; v.w *= inv;
  ((float4*)(ef + r * 256))[lane] = v;
  float4 a = ((const float4*)a2)[lane];
  float d = v.x * a.x + v.y * a.y + v.z * a.z + v.w * a.w;
  for (int o = 32; o; o >>= 1) d += __shfl_xor(d, o);
  if (lane == 0) s2[r] = d;
}

__device__ __forceinline__ unsigned f_sort(float f) {
  unsigned u = __float_as_uint(f);
  return (u & 0x80000000u) ? ~u : (u | 0x80000000u);
}
__device__ __forceinline__ float f_unsort(unsigned s) {
  return (s & 0x80000000u) ? __uint_as_float(s & 0x7FFFFFFFu) : __uint_as_float(~s);
}

__global__ void k_score(const float* __restrict__ s1, const float* __restrict__ s2,
                        const int* __restrict__ node, const int* __restrict__ edge,
                        float* __restrict__ score, unsigned* __restrict__ smax, int nE) {
  int e = blockIdx.x * blockDim.x + threadIdx.x;
  if (e >= nE) return;
  int n = node[e], ed = edge[e];
  float sc = lrelu(s1[n] + s2[ed]);
  score[e] = sc;
  atomicMax(&smax[n], f_sort(sc));
}

__global__ void k_expz(float* __restrict__ score, const unsigned* __restrict__ smax,
                       const int* __restrict__ node, float* __restrict__ z, int nE) {
  int e = blockIdx.x * blockDim.x + threadIdx.x;
  if (e >= nE) return;
  int n = node[e];
  float ex = __expf(score[e] - f_unsort(smax[n]));
  score[e] = ex;
  atomicAdd(&z[n], ex);
}

// attn = exps/z ; out[node] += attn * ef[edge]   (one wave per incidence)
__global__ __launch_bounds__(256) void k_attn_scatter(const float* __restrict__ exps,
                                                      const float* __restrict__ z,
                                                      const int* __restrict__ node,
                                                      const int* __restrict__ edge,
                                                      const float* __restrict__ ef,
                                                      float* __restrict__ outH,
                                                      float* __restrict__ attn_out, int nE) {
  int wave = threadIdx.x >> 6, lane = threadIdx.x & 63;
  size_t e = (size_t)blockIdx.x * 4 + wave;
  if (e >= (size_t)nE) return;
  int n = node[e], ed = edge[e];
  float at = exps[e] / fmaxf(z[n], 1e-9f);
  if (attn_out && lane == 0) attn_out[e] = at;
  float4 v = ((const float4*)(ef + (size_t)ed * 256))[lane];
  float* dp = outH + (size_t)n * 256 + lane * 4;
  atomicAdd(dp + 0, v.x * at);
  atomicAdd(dp + 1, v.y * at);
  atomicAdd(dp + 2, v.z * at);
  atomicAdd(dp + 3, v.w * at);
}

// lrelu rows -> bf16 and/or f32 (float4 granularity; in-place f32 OK)
__global__ void k_lrelu_rows(const float* __restrict__ src, unsigned short* dstb, float* dstf,
                             size_t n4) {
  size_t i = (size_t)blockIdx.x * blockDim.x + threadIdx.x;
  if (i >= n4) return;
  float4 v = ((const float4*)src)[i];
  v.x = lrelu(v.x); v.y = lrelu(v.y); v.z = lrelu(v.z); v.w = lrelu(v.w);
  if (dstf) ((float4*)dstf)[i] = v;
  if (dstb) {
    us4 u = {f2bf(v.x), f2bf(v.y), f2bf(v.z), f2bf(v.w)};
    ((us4*)dstb)[i] = u;
  }
}

// ---------------- driver ----------------

extern "C" void kernel_launch(void* const* d_in, const int* in_sizes, int n_in,
                              void* d_out, int out_size, void* d_ws, size_t ws_size,
                              hipStream_t stream) {
  (void)n_in; (void)out_size;
  const float* object_X = (const float*)d_in[0];
  const float* event_X = (const float*)d_in[1];
  const float* Wo = (const float*)d_in[2];   const float* bo = (const float*)d_in[3];
  const float* go = (const float*)d_in[4];   const float* bon = (const float*)d_in[5];
  const float* We = (const float*)d_in[6];   const float* be = (const float*)d_in[7];
  const float* ge = (const float*)d_in[8];   const float* ben = (const float*)d_in[9];
  const float* Wu = (const float*)d_in[10];  const float* bu = (const float*)d_in[11];
  const float* Wl = (const float*)d_in[12];  const float* bl = (const float*)d_in[13];
  const float* g1 = (const float*)d_in[14];  const float* b1 = (const float*)d_in[15];
  const float* g2 = (const float*)d_in[16];  const float* b2 = (const float*)d_in[17];
  const float* Wh1 = (const float*)d_in[18]; const float* ah1 = (const float*)d_in[19];
  const float* Wh2 = (const float*)d_in[20]; const float* ah2 = (const float*)d_in[21];
  const int* oe_ev = (const int*)d_in[22];
  const int* oe_obj = (const int*)d_in[23];
  const int* hg_node = (const int*)d_in[24];
  const int* hg_edge = (const int*)d_in[25];

  const int N_OBJ = in_sizes[0] / 256;
  const int N_EV = in_sizes[1] / 256;
  const int E1 = in_sizes[22];
  const int E2 = in_sizes[24];
  const int NN = N_EV + N_OBJ;
  const int MEV = ((N_EV + 63) / 64) * 64;
  const int MOB = ((N_OBJ + 63) / 64) * 64;
  const int MX = ((NN + 63) / 64) * 64;

  char* p = (char*)d_ws;
  auto take = [&](size_t bytes) {
    char* r = p;
    p += (bytes + 255) & ~(size_t)255;
    return r;
  };
  unsigned short* WT = (unsigned short*)take((size_t)6 * 65536 * 2);      // 0.79 MB
  unsigned short* XBF = (unsigned short*)take((size_t)MX * 256 * 2);      // 76.8 MB X/XW/h
  unsigned short* SB = (unsigned short*)take((size_t)MOB * 256 * 2);      // 51.2 MB staging
  float* EF = (float*)SB;                                                  // alias (SB dead then)
  unsigned short* OBJB = (unsigned short*)take((size_t)N_OBJ * 256 * 2);  // 51.2 MB obj skip
  int* CNT = (int*)take((size_t)N_EV * 4);
  float* S1 = (float*)take((size_t)NN * 4);
  float* S2 = (float*)take((size_t)N_EV * 4);
  float* SCORE = (float*)take((size_t)E2 * 4);
  unsigned* SMAX = (unsigned*)take((size_t)NN * 4);
  float* Z = (float*)take((size_t)NN * 4);
  size_t need = (size_t)(p - (char*)d_ws);
  if (need > ws_size)
    fprintf(stderr, "[kernel_launch] WS OVERFLOW: need=%zu have=%zu\n", need, ws_size);

  float* out = (float*)d_out;      // [NN*256] h, then [E2] attn
  float* MSG = (float*)d_out;      // scratch phase 1: E1 segment-sum target (N_OBJ rows)
  float* H = (float*)d_out;        // scratch phase 2: attn aggregation target (NN rows)

  // weights -> bf16 transposed
  k_transpose_w<<<256, 256, 0, stream>>>(We, WT + 0 * 65536);
  k_transpose_w<<<256, 256, 0, stream>>>(Wo, WT + 1 * 65536);
  k_transpose_w<<<256, 256, 0, stream>>>(Wu, WT + 2 * 65536);
  k_transpose_w<<<256, 256, 0, stream>>>(Wl, WT + 3 * 65536);
  k_transpose_w<<<256, 256, 0, stream>>>(Wh1, WT + 4 * 65536);
  k_transpose_w<<<256, 256, 0, stream>>>(Wh2, WT + 5 * 65536);

  // zero XBF pad rows (GEMM reads them; in-place XW writes are row-guarded so they stay 0)
  if (MX > NN)
    hipMemsetAsync(XBF + (size_t)NN * 256, 0, (size_t)(MX - NN) * 512, stream);

  // --- ev = LN(lrelu(event_X@We + be)) -> XBF rows [0,N_EV) bf16 ---
  k_f32_to_bf16<<<((size_t)MEV * 64 + 255) / 256, 256, 0, stream>>>(event_X, SB,
                                                                    (size_t)N_EV * 64,
                                                                    (size_t)MEV * 64);
  k_gemm_ln<0><<<MEV / 64, 256, 0, stream>>>(SB, WT + 0 * 65536, be, ge, ben, nullptr, XBF,
                                             N_EV);
  // --- obj = LN(lrelu(object_X@Wo + bo)) -> OBJB bf16 ---
  k_f32_to_bf16<<<((size_t)MOB * 64 + 255) / 256, 256, 0, stream>>>(object_X, SB,
                                                                    (size_t)N_OBJ * 64,
                                                                    (size_t)MOB * 64);
  k_gemm_ln<0><<<MOB / 64, 256, 0, stream>>>(SB, WT + 1 * 65536, bo, go, bon, nullptr, OBJB,
                                             N_OBJ);
  // --- msg = segment_sum(ev[oe_ev], oe_obj) in d_out; obj1 = LN(lrelu(msg@Wu+bu)+obj) -> SB ---
  hipMemsetAsync(MSG, 0, (size_t)N_OBJ * 1024, stream);
  k_scatter_bf<<<(E1 + 3) / 4, 256, 0, stream>>>(XBF, oe_ev, oe_obj, MSG, E1);
  k_f32_to_bf16<<<((size_t)MOB * 64 + 255) / 256, 256, 0, stream>>>(MSG, SB,
                                                                    (size_t)N_OBJ * 64,
                                                                    (size_t)MOB * 64);
  k_gemm_ln<1><<<MOB / 64, 256, 0, stream>>>(SB, WT + 2 * 65536, bu, g1, b1, OBJB, SB, N_OBJ);
  // --- obj2 = LN(lrelu(obj1@Wl+bl)+obj1) -> XBF rows [N_EV,NN) bf16 ---
  k_gemm_ln<1><<<MOB / 64, 256, 0, stream>>>(SB, WT + 3 * 65536, bl, g2, b2, SB,
                                             XBF + (size_t)N_EV * 256, N_OBJ);
  // --- hyperedge degrees (shared by both layers) ---
  hipMemsetAsync(CNT, 0, (size_t)N_EV * 4, stream);
  k_count<<<(E2 + 255) / 256, 256, 0, stream>>>(hg_edge, CNT, E2);

  // --- HGNN layer ---
  auto hgnn = [&](const unsigned short* WTl, const float* a, float* attn_out,
                  unsigned short* h_bf, float* h_f32) {
    k_gemm_xw<<<MX / 64, 256, 0, stream>>>(XBF, WTl, a, S1, NN);  // XW in-place + s1
    hipMemsetAsync(EF, 0, (size_t)N_EV * 1024, stream);
    k_scatter_bf<<<(E2 + 3) / 4, 256, 0, stream>>>(XBF, hg_node, hg_edge, EF, E2);
    k_ef_norm_s2<<<(N_EV + 3) / 4, 256, 0, stream>>>(EF, CNT, a + 256, S2, N_EV);
    hipMemsetAsync(SMAX, 0, (size_t)NN * 4, stream);
    hipMemsetAsync(Z, 0, (size_t)NN * 4, stream);
    k_score<<<(E2 + 255) / 256, 256, 0, stream>>>(S1, S2, hg_node, hg_edge, SCORE, SMAX, E2);
    k_expz<<<(E2 + 255) / 256, 256, 0, stream>>>(SCORE, SMAX, hg_node, Z, E2);
    hipMemsetAsync(H, 0, (size_t)NN * 1024, stream);
    k_attn_scatter<<<(E2 + 3) / 4, 256, 0, stream>>>(SCORE, Z, hg_node, hg_edge, EF, H,
                                                     attn_out, E2);
    size_t n4 = (size_t)NN * 64;
    k_lrelu_rows<<<(n4 + 255) / 256, 256, 0, stream>>>(H, h_bf, h_f32, n4);
  };

  hgnn(WT + 4 * 65536, ah1, nullptr, XBF, nullptr);                 // layer 1: h -> XBF bf16
  hgnn(WT + 5 * 65536, ah2, out + (size_t)NN * 256, nullptr, out);  // layer 2: h, attn -> d_out
}

// Round 3
// 2047.658 us; speedup vs baseline: 6.5037x; 6.5037x over previous
//
#include <hip/hip_runtime.h>
#include <cstdio>

typedef __attribute__((ext_vector_type(8))) short short8_t;
typedef __attribute__((ext_vector_type(8))) unsigned short ushort8_t;
typedef __attribute__((ext_vector_type(4))) unsigned short us4;
typedef __attribute__((ext_vector_type(4))) float f32x4;

__device__ __forceinline__ unsigned short f2bf(float f) {
  unsigned u = __float_as_uint(f);
  u = u + 0x7FFFu + ((u >> 16) & 1u);
  return (unsigned short)(u >> 16);
}
__device__ __forceinline__ float bf2f(unsigned short h) {
  return __uint_as_float((unsigned)h << 16);
}
__device__ __forceinline__ float lrelu(float x) { return x > 0.f ? x : 0.2f * x; }

// ---------------- conversion / transpose ----------------

__global__ void k_f32_to_bf16(const float* __restrict__ src, unsigned short* __restrict__ dst,
                              size_t ns4, size_t nd4) {
  size_t i = (size_t)blockIdx.x * blockDim.x + threadIdx.x;
  if (i >= nd4) return;
  float4 v = make_float4(0.f, 0.f, 0.f, 0.f);
  if (i < ns4) v = ((const float4*)src)[i];
  us4 u = {f2bf(v.x), f2bf(v.y), f2bf(v.z), f2bf(v.w)};
  ((us4*)dst)[i] = u;
}

__global__ void k_transpose_w(const float* __restrict__ W, unsigned short* __restrict__ Wt) {
  int k = blockIdx.x, n = threadIdx.x;
  Wt[n * 256 + k] = f2bf(W[k * 256 + n]);
}

// ---------------- CSR build ----------------

__global__ void k_count(const int* __restrict__ idx, int* __restrict__ cnt, int nE) {
  int e = blockIdx.x * blockDim.x + threadIdx.x;
  if (e < nE) atomicAdd(&cnt[idx[e]], 1);
}

// single-block exclusive scan: starts[0..n] (starts[n] = total). block = 1024.
__global__ __launch_bounds__(1024) void k_scan_excl(const int* __restrict__ cnt,
                                                    int* __restrict__ starts, int n) {
  __shared__ int wsum[16];
  int tid = threadIdx.x, lane = tid & 63, w = tid >> 6;
  int carry = 0;
  for (int base = 0; base < n; base += 4096) {
    int i0 = base + tid * 4;
    int4 c = make_int4(0, 0, 0, 0);
    if (i0 + 3 < n) c = *(const int4*)(cnt + i0);
    else {
      if (i0 < n) c.x = cnt[i0];
      if (i0 + 1 < n) c.y = cnt[i0 + 1];
      if (i0 + 2 < n) c.z = cnt[i0 + 2];
      if (i0 + 3 < n) c.w = cnt[i0 + 3];
    }
    int tsum = c.x + c.y + c.z + c.w;
    int inc = tsum;
    for (int o = 1; o < 64; o <<= 1) {
      int v = __shfl_up(inc, o);
      if (lane >= o) inc += v;
    }
    if (lane == 63) wsum[w] = inc;
    __syncthreads();
    int woff = 0;
    for (int k = 0; k < w; k++) woff += wsum[k];
    int excl = carry + woff + inc - tsum;
    if (i0 < n) starts[i0] = excl;
    if (i0 + 1 < n) starts[i0 + 1] = excl + c.x;
    if (i0 + 2 < n) starts[i0 + 2] = excl + c.x + c.y;
    if (i0 + 3 < n) starts[i0 + 3] = excl + c.x + c.y + c.z;
    int total = 0;
    for (int k = 0; k < 16; k++) total += wsum[k];
    carry += total;
    __syncthreads();
  }
  if (tid == 0) starts[n] = carry;
}

__global__ void k_fill(const int* __restrict__ idx, const int* __restrict__ starts,
                       int* __restrict__ cur, int* __restrict__ perm, int nE) {
  int e = blockIdx.x * blockDim.x + threadIdx.x;
  if (e >= nE) return;
  int s = idx[e];
  int p = starts[s] + atomicAdd(&cur[s], 1);
  perm[p] = e;
}

// ---------------- fused GEMM (+bias+lrelu+skip+LN) ------------------------------------
template <int HAS_SKIP>
__global__ __launch_bounds__(256) void k_gemm_ln(const unsigned short* A,
                                                 const unsigned short* __restrict__ Bt,
                                                 const float* __restrict__ bias,
                                                 const float* __restrict__ gamma,
                                                 const float* __restrict__ beta,
                                                 const unsigned short* skip,
                                                 unsigned short* outb, int rows) {
  __shared__ unsigned short As[64][40];
  __shared__ unsigned short Bs[256][40];
  int tid = threadIdx.x;
  int wave = tid >> 6, lane = tid & 63;
  int quad = lane >> 4, l16 = lane & 15;
  size_t row0 = (size_t)blockIdx.x * 64;

  f32x4 acc[16];
#pragma unroll
  for (int i = 0; i < 16; i++) acc[i] = (f32x4){0.f, 0.f, 0.f, 0.f};

  int ar = tid >> 2, ac = (tid & 3) * 8;
  for (int k0 = 0; k0 < 256; k0 += 32) {
    *(ushort8_t*)&As[ar][ac] = *(const ushort8_t*)&A[(row0 + ar) * 256 + k0 + ac];
    const unsigned short* bp = &Bt[(size_t)tid * 256 + k0];
    *(ushort8_t*)&Bs[tid][0] = *(const ushort8_t*)&bp[0];
    *(ushort8_t*)&Bs[tid][8] = *(const ushort8_t*)&bp[8];
    *(ushort8_t*)&Bs[tid][16] = *(const ushort8_t*)&bp[16];
    *(ushort8_t*)&Bs[tid][24] = *(const ushort8_t*)&bp[24];
    __syncthreads();
    short8_t afrag = *(const short8_t*)&As[wave * 16 + l16][quad * 8];
#pragma unroll
    for (int nt = 0; nt < 16; nt++) {
      short8_t bfrag = *(const short8_t*)&Bs[nt * 16 + l16][quad * 8];
      acc[nt] = __builtin_amdgcn_mfma_f32_16x16x32_bf16(afrag, bfrag, acc[nt], 0, 0, 0);
    }
    __syncthreads();
  }

  size_t rbase = row0 + wave * 16 + quad * 4;
#pragma unroll
  for (int nt = 0; nt < 16; nt++) {
    int col = nt * 16 + l16;
    float bv = bias[col];
#pragma unroll
    for (int r = 0; r < 4; r++) {
      float x = lrelu(acc[nt][r] + bv);
      if (HAS_SKIP) {
        if (rbase + r < (size_t)rows) x += bf2f(skip[(rbase + r) * 256 + col]);
      }
      acc[nt][r] = x;
    }
  }
  float s[4] = {0, 0, 0, 0}, q[4] = {0, 0, 0, 0};
#pragma unroll
  for (int nt = 0; nt < 16; nt++)
#pragma unroll
    for (int r = 0; r < 4; r++) {
      float x = acc[nt][r];
      s[r] += x;
      q[r] += x * x;
    }
#pragma unroll
  for (int o = 1; o < 16; o <<= 1)
#pragma unroll
    for (int r = 0; r < 4; r++) {
      s[r] += __shfl_xor(s[r], o);
      q[r] += __shfl_xor(q[r], o);
    }
  float mr[4], rs[4];
#pragma unroll
  for (int r = 0; r < 4; r++) {
    float m = s[r] * (1.f / 256.f);
    float v = q[r] * (1.f / 256.f) - m * m;
    mr[r] = m;
    rs[r] = rsqrtf(v + 1e-5f);
  }
#pragma unroll
  for (int nt = 0; nt < 16; nt++) {
    int col = nt * 16 + l16;
    float g = gamma[col], bb = beta[col];
#pragma unroll
    for (int r = 0; r < 4; r++) {
      if (rbase + r < (size_t)rows) {
        float y = (acc[nt][r] - mr[r]) * rs[r] * g + bb;
        outb[(rbase + r) * 256 + col] = f2bf(y);
      }
    }
  }
}

// ---------------- fused GEMM for HGNN: XW (bf16, in-place) + s1 = XW@a1 ----------
__global__ __launch_bounds__(256) void k_gemm_xw(unsigned short* A,
                                                 const unsigned short* __restrict__ Bt,
                                                 const float* __restrict__ a1,
                                                 float* __restrict__ s1, int rows) {
  __shared__ unsigned short As[64][40];
  __shared__ unsigned short Bs[256][40];
  int tid = threadIdx.x;
  int wave = tid >> 6, lane = tid & 63;
  int quad = lane >> 4, l16 = lane & 15;
  size_t row0 = (size_t)blockIdx.x * 64;

  f32x4 acc[16];
#pragma unroll
  for (int i = 0; i < 16; i++) acc[i] = (f32x4){0.f, 0.f, 0.f, 0.f};

  int ar = tid >> 2, ac = (tid & 3) * 8;
  for (int k0 = 0; k0 < 256; k0 += 32) {
    *(ushort8_t*)&As[ar][ac] = *(const ushort8_t*)&A[(row0 + ar) * 256 + k0 + ac];
    const unsigned short* bp = &Bt[(size_t)tid * 256 + k0];
    *(ushort8_t*)&Bs[tid][0] = *(const ushort8_t*)&bp[0];
    *(ushort8_t*)&Bs[tid][8] = *(const ushort8_t*)&bp[8];
    *(ushort8_t*)&Bs[tid][16] = *(const ushort8_t*)&bp[16];
    *(ushort8_t*)&Bs[tid][24] = *(const ushort8_t*)&bp[24];
    __syncthreads();
    short8_t afrag = *(const short8_t*)&As[wave * 16 + l16][quad * 8];
#pragma unroll
    for (int nt = 0; nt < 16; nt++) {
      short8_t bfrag = *(const short8_t*)&Bs[nt * 16 + l16][quad * 8];
      acc[nt] = __builtin_amdgcn_mfma_f32_16x16x32_bf16(afrag, bfrag, acc[nt], 0, 0, 0);
    }
    __syncthreads();
  }

  size_t rbase = row0 + wave * 16 + quad * 4;
  float s[4] = {0, 0, 0, 0};
#pragma unroll
  for (int nt = 0; nt < 16; nt++) {
    float av = a1[nt * 16 + l16];
#pragma unroll
    for (int r = 0; r < 4; r++) s[r] += acc[nt][r] * av;
  }
#pragma unroll
  for (int o = 1; o < 16; o <<= 1)
#pragma unroll
    for (int r = 0; r < 4; r++) s[r] += __shfl_xor(s[r], o);
#pragma unroll
  for (int nt = 0; nt < 16; nt++) {
    int col = nt * 16 + l16;
#pragma unroll
    for (int r = 0; r < 4; r++)
      if (rbase + r < (size_t)rows) A[(rbase + r) * 256 + col] = f2bf(acc[nt][r]);
  }
  if (l16 == 0) {
#pragma unroll
    for (int r = 0; r < 4; r++)
      if (rbase + r < (size_t)rows) s1[rbase + r] = s[r];
  }
}

// ---------------- CSR gathers ----------------

// per hyperedge r (one wave): ef[r] = mean of XW[node] rows; s2[r] = ef[r]·a2
__global__ __launch_bounds__(256) void k_edge_gather(const unsigned short* __restrict__ XW,
                                                     const int* __restrict__ ES,
                                                     const int* __restrict__ perm,
                                                     const int* __restrict__ hg_node,
                                                     const float* __restrict__ a2,
                                                     float* __restrict__ EF,
                                                     float* __restrict__ s2, int nEdges) {
  int wave = threadIdx.x >> 6, lane = threadIdx.x & 63;
  int r = blockIdx.x * 4 + wave;
  if (r >= nEdges) return;
  int s = ES[r], e = ES[r + 1];
  float4 acc = make_float4(0.f, 0.f, 0.f, 0.f);
  for (int j = s; j < e; j++) {
    int n = hg_node[perm[j]];
    us4 u = ((const us4*)(XW + (size_t)n * 256))[lane];
    acc.x += bf2f(u.x); acc.y += bf2f(u.y);
    acc.z += bf2f(u.z); acc.w += bf2f(u.w);
  }
  int c = e - s;
  float inv = 1.f / (float)(c > 1 ? c : 1);
  acc.x *= inv; acc.y *= inv; acc.z *= inv; acc.w *= inv;
  ((float4*)(EF + (size_t)r * 256))[lane] = acc;
  float4 a = ((const float4*)a2)[lane];
  float d = acc.x * a.x + acc.y * a.y + acc.z * a.z + acc.w * a.w;
  for (int o = 32; o; o >>= 1) d += __shfl_xor(d, o);
  if (lane == 0) s2[r] = d;
}

// per node n (one wave): in-wave softmax over incidences + weighted EF gather + lrelu
template <int WRITE_ATTN>
__global__ __launch_bounds__(256) void k_node_gather(const int* __restrict__ NS,
                                                     const int* __restrict__ perm,
                                                     const int* __restrict__ hg_edge,
                                                     const float* __restrict__ s1,
                                                     const float* __restrict__ s2,
                                                     const float* __restrict__ EF,
                                                     unsigned short* outb, float* outf,
                                                     float* attn_out, int nNodes) {
  int wave = threadIdx.x >> 6, lane = threadIdx.x & 63;
  int n = blockIdx.x * 4 + wave;
  if (n >= nNodes) return;
  int s = NS[n], e = NS[n + 1];
  float s1n = s1[n];
  float mymax = -3.4e38f;
  for (int j = s + lane; j < e; j += 64) {
    int ed = hg_edge[perm[j]];
    mymax = fmaxf(mymax, lrelu(s1n + s2[ed]));
  }
  for (int o = 32; o; o >>= 1) mymax = fmaxf(mymax, __shfl_xor(mymax, o));
  float mysum = 0.f;
  for (int j = s + lane; j < e; j += 64) {
    int ed = hg_edge[perm[j]];
    mysum += __expf(lrelu(s1n + s2[ed]) - mymax);
  }
  for (int o = 32; o; o >>= 1) mysum += __shfl_xor(mysum, o);
  float zinv = 1.f / fmaxf(mysum, 1e-9f);
  float4 acc = make_float4(0.f, 0.f, 0.f, 0.f);
  for (int j = s; j < e; j++) {
    int e0 = perm[j];
    int ed = hg_edge[e0];
    float w = __expf(lrelu(s1n + s2[ed]) - mymax) * zinv;
    if (WRITE_ATTN) {
      if (lane == 0) attn_out[e0] = w;
    }
    float4 v = ((const float4*)(EF + (size_t)ed * 256))[lane];
    acc.x += w * v.x; acc.y += w * v.y;
    acc.z += w * v.z; acc.w += w * v.w;
  }
  acc.x = lrelu(acc.x); acc.y = lrelu(acc.y);
  acc.z = lrelu(acc.z); acc.w = lrelu(acc.w);
  if (outb) {
    us4 u = {f2bf(acc.x), f2bf(acc.y), f2bf(acc.z), f2bf(acc.w)};
    ((us4*)(outb + (size_t)n * 256))[lane] = u;
  } else {
    ((float4*)(outf + (size_t)n * 256))[lane] = acc;
  }
}

// per object o (one wave): msg[o] = sum of ev rows (bf16 in, bf16 out)
__global__ __launch_bounds__(256) void k_obj_gather(const unsigned short* __restrict__ EVB,
                                                    const int* __restrict__ OS,
                                                    const int* __restrict__ perm,
                                                    const int* __restrict__ oe_ev,
                                                    unsigned short* __restrict__ outb,
                                                    int nObj) {
  int wave = threadIdx.x >> 6, lane = threadIdx.x & 63;
  int o = blockIdx.x * 4 + wave;
  if (o >= nObj) return;
  int s = OS[o], e = OS[o + 1];
  float4 acc = make_float4(0.f, 0.f, 0.f, 0.f);
  for (int j = s; j < e; j++) {
    int ev = oe_ev[perm[j]];
    us4 u = ((const us4*)(EVB + (size_t)ev * 256))[lane];
    acc.x += bf2f(u.x); acc.y += bf2f(u.y);
    acc.z += bf2f(u.z); acc.w += bf2f(u.w);
  }
  us4 u = {f2bf(acc.x), f2bf(acc.y), f2bf(acc.z), f2bf(acc.w)};
  ((us4*)(outb + (size_t)o * 256))[lane] = u;
}

// ---------------- driver ----------------

extern "C" void kernel_launch(void* const* d_in, const int* in_sizes, int n_in,
                              void* d_out, int out_size, void* d_ws, size_t ws_size,
                              hipStream_t stream) {
  (void)n_in; (void)out_size;
  const float* object_X = (const float*)d_in[0];
  const float* event_X = (const float*)d_in[1];
  const float* Wo = (const float*)d_in[2];   const float* bo = (const float*)d_in[3];
  const float* go = (const float*)d_in[4];   const float* bon = (const float*)d_in[5];
  const float* We = (const float*)d_in[6];   const float* be = (const float*)d_in[7];
  const float* ge = (const float*)d_in[8];   const float* ben = (const float*)d_in[9];
  const float* Wu = (const float*)d_in[10];  const float* bu = (const float*)d_in[11];
  const float* Wl = (const float*)d_in[12];  const float* bl = (const float*)d_in[13];
  const float* g1 = (const float*)d_in[14];  const float* b1 = (const float*)d_in[15];
  const float* g2 = (const float*)d_in[16];  const float* b2 = (const float*)d_in[17];
  const float* Wh1 = (const float*)d_in[18]; const float* ah1 = (const float*)d_in[19];
  const float* Wh2 = (const float*)d_in[20]; const float* ah2 = (const float*)d_in[21];
  const int* oe_ev = (const int*)d_in[22];
  const int* oe_obj = (const int*)d_in[23];
  const int* hg_node = (const int*)d_in[24];
  const int* hg_edge = (const int*)d_in[25];

  const int N_OBJ = in_sizes[0] / 256;
  const int N_EV = in_sizes[1] / 256;
  const int E1 = in_sizes[22];
  const int E2 = in_sizes[24];
  const int NN = N_EV + N_OBJ;
  const int MEV = ((N_EV + 63) / 64) * 64;
  const int MOB = ((N_OBJ + 63) / 64) * 64;
  const int MX = ((NN + 63) / 64) * 64;

  char* p = (char*)d_ws;
  auto take = [&](size_t bytes) {
    char* r = p;
    p += (bytes + 255) & ~(size_t)255;
    return r;
  };
  unsigned short* WT = (unsigned short*)take((size_t)6 * 65536 * 2);  // 0.79 MB
  unsigned short* XBF = (unsigned short*)take((size_t)MX * 256 * 2);  // 76.8 MB  X / XW / h
  unsigned short* SB = (unsigned short*)take((size_t)MOB * 256 * 2);  // 51.2 MB staging
  float* EF = (float*)SB;  // alias: SB dead once the obj2 GEMM has consumed it
  float* S1 = (float*)take((size_t)NN * 4);
  float* S2 = (float*)take((size_t)N_EV * 4);
  int* NS = (int*)take((size_t)(NN + 1) * 4);      // node CSR starts
  int* ES = (int*)take((size_t)(N_EV + 1) * 4);    // edge CSR starts
  int* OS = (int*)take((size_t)(N_OBJ + 1) * 4);   // obj CSR starts
  int* CNTn = (int*)take((size_t)NN * 4);          // counts, reused as fill cursors
  int* CNTe = (int*)take((size_t)N_EV * 4);
  int* CNTo = (int*)take((size_t)N_OBJ * 4);
  int* PERMn = (int*)take((size_t)E2 * 4);
  int* PERMe = (int*)take((size_t)E2 * 4);
  int* PERMo = (int*)take((size_t)E1 * 4);
  size_t need = (size_t)(p - (char*)d_ws);
  if (need > ws_size)
    fprintf(stderr, "[kernel_launch] WS OVERFLOW: need=%zu have=%zu\n", need, ws_size);

  float* out = (float*)d_out;
  // obj skip (bf16, 51.2 MB) lives in d_out — dead region until layer-2 outputs
  unsigned short* OBJB = (unsigned short*)d_out;

  // --- weights -> bf16 transposed ---
  k_transpose_w<<<256, 256, 0, stream>>>(We, WT + 0 * 65536);
  k_transpose_w<<<256, 256, 0, stream>>>(Wo, WT + 1 * 65536);
  k_transpose_w<<<256, 256, 0, stream>>>(Wu, WT + 2 * 65536);
  k_transpose_w<<<256, 256, 0, stream>>>(Wl, WT + 3 * 65536);
  k_transpose_w<<<256, 256, 0, stream>>>(Wh1, WT + 4 * 65536);
  k_transpose_w<<<256, 256, 0, stream>>>(Wh2, WT + 5 * 65536);

  if (MX > NN)
    hipMemsetAsync(XBF + (size_t)NN * 256, 0, (size_t)(MX - NN) * 512, stream);

  // --- CSR builds (node/E2, edge/E2, obj/E1) ---
  hipMemsetAsync(CNTn, 0, (size_t)NN * 4, stream);
  hipMemsetAsync(CNTe, 0, (size_t)N_EV * 4, stream);
  hipMemsetAsync(CNTo, 0, (size_t)N_OBJ * 4, stream);
  k_count<<<(E2 + 255) / 256, 256, 0, stream>>>(hg_node, CNTn, E2);
  k_count<<<(E2 + 255) / 256, 256, 0, stream>>>(hg_edge, CNTe, E2);
  k_count<<<(E1 + 255) / 256, 256, 0, stream>>>(oe_obj, CNTo, E1);
  k_scan_excl<<<1, 1024, 0, stream>>>(CNTn, NS, NN);
  k_scan_excl<<<1, 1024, 0, stream>>>(CNTe, ES, N_EV);
  k_scan_excl<<<1, 1024, 0, stream>>>(CNTo, OS, N_OBJ);
  hipMemsetAsync(CNTn, 0, (size_t)NN * 4, stream);
  hipMemsetAsync(CNTe, 0, (size_t)N_EV * 4, stream);
  hipMemsetAsync(CNTo, 0, (size_t)N_OBJ * 4, stream);
  k_fill<<<(E2 + 255) / 256, 256, 0, stream>>>(hg_node, NS, CNTn, PERMn, E2);
  k_fill<<<(E2 + 255) / 256, 256, 0, stream>>>(hg_edge, ES, CNTe, PERMe, E2);
  k_fill<<<(E1 + 255) / 256, 256, 0, stream>>>(oe_obj, OS, CNTo, PERMo, E1);

  // --- ev = LN(lrelu(event_X@We + be)) -> XBF rows [0,N_EV) bf16 ---
  k_f32_to_bf16<<<((size_t)MEV * 64 + 255) / 256, 256, 0, stream>>>(
      event_X, SB, (size_t)N_EV * 64, (size_t)MEV * 64);
  k_gemm_ln<0><<<MEV / 64, 256, 0, stream>>>(SB, WT + 0 * 65536, be, ge, ben, nullptr, XBF,
                                             N_EV);
  // --- obj = LN(lrelu(object_X@Wo + bo)) -> OBJB bf16 (in d_out) ---
  k_f32_to_bf16<<<((size_t)MOB * 64 + 255) / 256, 256, 0, stream>>>(
      object_X, SB, (size_t)N_OBJ * 64, (size_t)MOB * 64);
  k_gemm_ln<0><<<MOB / 64, 256, 0, stream>>>(SB, WT + 1 * 65536, bo, go, bon, nullptr, OBJB,
                                             N_OBJ);
  // --- msg (CSR gather, bf16) -> SB; obj1 = LN(lrelu(msg@Wu+bu)+obj) -> SB ---
  k_obj_gather<<<(N_OBJ + 3) / 4, 256, 0, stream>>>(XBF, OS, PERMo, oe_ev, SB, N_OBJ);
  k_gemm_ln<1><<<MOB / 64, 256, 0, stream>>>(SB, WT + 2 * 65536, bu, g1, b1, OBJB, SB, N_OBJ);
  // --- obj2 = LN(lrelu(obj1@Wl+bl)+obj1) -> XBF rows [N_EV,NN) bf16 ---
  k_gemm_ln<1><<<MOB / 64, 256, 0, stream>>>(SB, WT + 3 * 65536, bl, g2, b2, SB,
                                             XBF + (size_t)N_EV * 256, N_OBJ);

  // --- HGNN layer 1: h -> XBF bf16 (SB now dead; EF aliases it) ---
  k_gemm_xw<<<MX / 64, 256, 0, stream>>>(XBF, WT + 4 * 65536, ah1, S1, NN);
  k_edge_gather<<<(N_EV + 3) / 4, 256, 0, stream>>>(XBF, ES, PERMe, hg_node, ah1 + 256, EF,
                                                    S2, N_EV);
  k_node_gather<0><<<(NN + 3) / 4, 256, 0, stream>>>(NS, PERMn, hg_edge, S1, S2, EF, XBF,
                                                     nullptr, nullptr, NN);
  // --- HGNN layer 2: h f32 + attn -> d_out ---
  k_gemm_xw<<<MX / 64, 256, 0, stream>>>(XBF, WT + 5 * 65536, ah2, S1, NN);
  k_edge_gather<<<(N_EV + 3) / 4, 256, 0, stream>>>(XBF, ES, PERMe, hg_node, ah2 + 256, EF,
                                                    S2, N_EV);
  k_node_gather<1><<<(NN + 3) / 4, 256, 0, stream>>>(NS, PERMn, hg_edge, S1, S2, EF, nullptr,
                                                     out, out + (size_t)NN * 256, NN);
}